// Round 16
// baseline (628.334 us; speedup 1.0000x reference)
//
#include <hip/hip_runtime.h>
#include <math.h>

#define NBATCH 8
#define NTOK   4096
#define DIMX   512
#define QKVC   1536   // 3*8*64
#define DH     64
#define SCALE  0.125f // 64^-0.5

typedef __attribute__((ext_vector_type(8))) short short8;
typedef __attribute__((ext_vector_type(4))) float f32x4;
typedef __attribute__((ext_vector_type(4))) unsigned short us4;

static __device__ __forceinline__ unsigned short f2bf_hi(float f) {
    unsigned u = __float_as_uint(f);
    return (unsigned short)((u + 0x8000u) >> 16);
}
static __device__ __forceinline__ unsigned short f2bf_lo(float f, unsigned short hi) {
    float hf = __uint_as_float(((unsigned)hi) << 16);
    return (unsigned short)(__float_as_uint(f - hf) >> 16);
}

// ============== Pre-pass: split X into bf16 hi/lo planes (stored in d_out) ==============
__global__ __launch_bounds__(256) void split_x(const float* __restrict__ X,
                                               unsigned short* __restrict__ XH,
                                               unsigned short* __restrict__ XL) {
    size_t i = (size_t)blockIdx.x * 256 + threadIdx.x;   // one float4 per thread
    float4 v = *(const float4*)(X + i * 4);
    unsigned short h0 = f2bf_hi(v.x), h1 = f2bf_hi(v.y), h2 = f2bf_hi(v.z), h3 = f2bf_hi(v.w);
    us4 H = {h0, h1, h2, h3};
    us4 L = {f2bf_lo(v.x, h0), f2bf_lo(v.y, h1), f2bf_lo(v.z, h2), f2bf_lo(v.w, h3)};
    *(us4*)(XH + i * 4) = H;
    *(us4*)(XL + i * 4) = L;
}

// ============== QKV GEMM via MFMA, split-bf16 ==============
// ROUND-14 BUG (absmax 0.83): Wp dropped the "* 8" -> staged wrong W rows.
// Fixed; this line must match the LDS store at k-positions bkg*8..bkg*8+7.
#define BF_PACKC(H, L, C) do {                                                  \
    unsigned short h0=f2bf_hi(lb0.C),h1=f2bf_hi(lb1.C),h2=f2bf_hi(lb2.C),h3=f2bf_hi(lb3.C); \
    unsigned short h4=f2bf_hi(lb4.C),h5=f2bf_hi(lb5.C),h6=f2bf_hi(lb6.C),h7=f2bf_hi(lb7.C); \
    H[0]=(short)h0; H[1]=(short)h1; H[2]=(short)h2; H[3]=(short)h3;             \
    H[4]=(short)h4; H[5]=(short)h5; H[6]=(short)h6; H[7]=(short)h7;             \
    L[0]=(short)f2bf_lo(lb0.C,h0); L[1]=(short)f2bf_lo(lb1.C,h1);               \
    L[2]=(short)f2bf_lo(lb2.C,h2); L[3]=(short)f2bf_lo(lb3.C,h3);               \
    L[4]=(short)f2bf_lo(lb4.C,h4); L[5]=(short)f2bf_lo(lb5.C,h5);               \
    L[6]=(short)f2bf_lo(lb6.C,h6); L[7]=(short)f2bf_lo(lb7.C,h7);               \
} while (0)

__global__ __launch_bounds__(256, 2) void qkv_gemm_mfma(const unsigned short* __restrict__ XH,
                                                        const unsigned short* __restrict__ XL,
                                                        const float* __restrict__ W,
                                                        float* __restrict__ QKV) {
    __shared__ short Ah[128 * 64];
    __shared__ short Al[128 * 64];
    __shared__ short Bh[128 * 64];   // [col][k] (transposed W)
    __shared__ short Bl[128 * 64];

    const int t    = threadIdx.x;
    const int bm   = blockIdx.x & 255;
    const int bn   = blockIdx.x >> 8;
    const int m0   = bm * 128, n0 = bn * 128;
    const int lane = t & 63;
    const int wv   = t >> 6, wr = wv >> 1, wc = wv & 1;
    const int lr   = lane & 15, kg4 = lane >> 4;

    const int arow = t >> 1, ahalf = t & 1;   // A: row, 32-k half
    const int bkg  = t & 7,  bcg   = t >> 3;  // B: 8 k-rows x 4 cols

    f32x4 acc[4][4];
#pragma unroll
    for (int i = 0; i < 4; ++i)
#pragma unroll
        for (int j = 0; j < 4; ++j) acc[i][j] = (f32x4){0.f, 0.f, 0.f, 0.f};

    const unsigned short* XHp = XH + (size_t)(m0 + arow) * DIMX + ahalf * 32;
    const unsigned short* XLp = XL + (size_t)(m0 + arow) * DIMX + ahalf * 32;
    const float* Wp = W + (size_t)bkg * 8 * QKVC + n0 + bcg * 4;   // <-- the fixed "* 8"

    for (int k0 = 0; k0 < DIMX; k0 += 64) {
        // ---- A: plain bf16 plane loads (no pack)
        short8 ha0 = *(const short8*)(XHp + k0 +  0);
        short8 ha1 = *(const short8*)(XHp + k0 +  8);
        short8 ha2 = *(const short8*)(XHp + k0 + 16);
        short8 ha3 = *(const short8*)(XHp + k0 + 24);
        short8 la0 = *(const short8*)(XLp + k0 +  0);
        short8 la1 = *(const short8*)(XLp + k0 +  8);
        short8 la2 = *(const short8*)(XLp + k0 + 16);
        short8 la3 = *(const short8*)(XLp + k0 + 24);
        // ---- B: fp32 W loads (transpose+split in pack below)
        const float* Wk = Wp + (size_t)k0 * QKVC;
        float4 lb0 = *(const float4*)(Wk + 0 * QKVC);
        float4 lb1 = *(const float4*)(Wk + 1 * QKVC);
        float4 lb2 = *(const float4*)(Wk + 2 * QKVC);
        float4 lb3 = *(const float4*)(Wk + 3 * QKVC);
        float4 lb4 = *(const float4*)(Wk + 4 * QKVC);
        float4 lb5 = *(const float4*)(Wk + 5 * QKVC);
        float4 lb6 = *(const float4*)(Wk + 6 * QKVC);
        float4 lb7 = *(const float4*)(Wk + 7 * QKVC);

        __syncthreads();   // previous iteration's fragment reads done

        {
            const int sw = (arow & 7) << 3;
            int i0 = arow * 64 + ((ahalf * 32 +  0) ^ sw);
            int i1 = arow * 64 + ((ahalf * 32 +  8) ^ sw);
            int i2 = arow * 64 + ((ahalf * 32 + 16) ^ sw);
            int i3 = arow * 64 + ((ahalf * 32 + 24) ^ sw);
            *(short8*)&Ah[i0] = ha0; *(short8*)&Al[i0] = la0;
            *(short8*)&Ah[i1] = ha1; *(short8*)&Al[i1] = la1;
            *(short8*)&Ah[i2] = ha2; *(short8*)&Al[i2] = la2;
            *(short8*)&Ah[i3] = ha3; *(short8*)&Al[i3] = la3;
        }
        {
            short8 H, L;
            { int col = bcg * 4 + 0; int idx = col * 64 + ((bkg * 8) ^ ((col & 7) << 3));
              BF_PACKC(H, L, x); *(short8*)&Bh[idx] = H; *(short8*)&Bl[idx] = L; }
            { int col = bcg * 4 + 1; int idx = col * 64 + ((bkg * 8) ^ ((col & 7) << 3));
              BF_PACKC(H, L, y); *(short8*)&Bh[idx] = H; *(short8*)&Bl[idx] = L; }
            { int col = bcg * 4 + 2; int idx = col * 64 + ((bkg * 8) ^ ((col & 7) << 3));
              BF_PACKC(H, L, z); *(short8*)&Bh[idx] = H; *(short8*)&Bl[idx] = L; }
            { int col = bcg * 4 + 3; int idx = col * 64 + ((bkg * 8) ^ ((col & 7) << 3));
              BF_PACKC(H, L, w); *(short8*)&Bh[idx] = H; *(short8*)&Bl[idx] = L; }
        }
        __syncthreads();   // tile ready

#pragma unroll
        for (int ks = 0; ks < 2; ++ks) {
            short8 a_h[4], a_l[4], b_h[4], b_l[4];
#pragma unroll
            for (int fm = 0; fm < 4; ++fm) {
                int row = wr * 64 + fm * 16 + lr;
                int idx = row * 64 + ((ks * 32 + kg4 * 8) ^ ((row & 7) << 3));
                a_h[fm] = *(const short8*)&Ah[idx];
                a_l[fm] = *(const short8*)&Al[idx];
            }
#pragma unroll
            for (int fn = 0; fn < 4; ++fn) {
                int col = wc * 64 + fn * 16 + lr;
                int idx = col * 64 + ((ks * 32 + kg4 * 8) ^ ((col & 7) << 3));
                b_h[fn] = *(const short8*)&Bh[idx];
                b_l[fn] = *(const short8*)&Bl[idx];
            }
#pragma unroll
            for (int fm = 0; fm < 4; ++fm)
#pragma unroll
                for (int fn = 0; fn < 4; ++fn) {
                    acc[fm][fn] = __builtin_amdgcn_mfma_f32_16x16x32_bf16(
                        a_h[fm], b_h[fn], acc[fm][fn], 0, 0, 0);
                    acc[fm][fn] = __builtin_amdgcn_mfma_f32_16x16x32_bf16(
                        a_h[fm], b_l[fn], acc[fm][fn], 0, 0, 0);
                    acc[fm][fn] = __builtin_amdgcn_mfma_f32_16x16x32_bf16(
                        a_l[fm], b_h[fn], acc[fm][fn], 0, 0, 0);
                }
        }
    }

#pragma unroll
    for (int fm = 0; fm < 4; ++fm)
#pragma unroll
        for (int fn = 0; fn < 4; ++fn) {
            int col = n0 + wc * 64 + fn * 16 + lr;
#pragma unroll
            for (int j = 0; j < 4; ++j) {
                int row = m0 + wr * 64 + fm * 16 + kg4 * 4 + j;
                QKV[(size_t)row * QKVC + col] = acc[fm][fn][j];
            }
        }
}

// ================= Spatial attention v2: 2 query rows per thread ==============
#define QDOT2(JJ, SA, SB) do {                                                  \
    const float* kr_ = &Ks[k0 + (JJ)][l16];                                     \
    float4 k0_ = *(const float4*)(kr_);      float4 k1_ = *(const float4*)(kr_ + 4);  \
    float4 k2_ = *(const float4*)(kr_ + 8);  float4 k3_ = *(const float4*)(kr_ + 12); \
    float dA_ = qa0.x * k0_.x;                                                  \
    dA_ = fmaf(qa0.y, k0_.y, dA_); dA_ = fmaf(qa0.z, k0_.z, dA_); dA_ = fmaf(qa0.w, k0_.w, dA_); \
    dA_ = fmaf(qb0.x, k1_.x, dA_); dA_ = fmaf(qb0.y, k1_.y, dA_); dA_ = fmaf(qb0.z, k1_.z, dA_); dA_ = fmaf(qb0.w, k1_.w, dA_); \
    dA_ = fmaf(qc0.x, k2_.x, dA_); dA_ = fmaf(qc0.y, k2_.y, dA_); dA_ = fmaf(qc0.z, k2_.z, dA_); dA_ = fmaf(qc0.w, k2_.w, dA_); \
    dA_ = fmaf(qd0.x, k3_.x, dA_); dA_ = fmaf(qd0.y, k3_.y, dA_); dA_ = fmaf(qd0.z, k3_.z, dA_); dA_ = fmaf(qd0.w, k3_.w, dA_); \
    float dB_ = qa1.x * k0_.x;                                                  \
    dB_ = fmaf(qa1.y, k0_.y, dB_); dB_ = fmaf(qa1.z, k0_.z, dB_); dB_ = fmaf(qa1.w, k0_.w, dB_); \
    dB_ = fmaf(qb1.x, k1_.x, dB_); dB_ = fmaf(qb1.y, k1_.y, dB_); dB_ = fmaf(qb1.z, k1_.z, dB_); dB_ = fmaf(qb1.w, k1_.w, dB_); \
    dB_ = fmaf(qc1.x, k2_.x, dB_); dB_ = fmaf(qc1.y, k2_.y, dB_); dB_ = fmaf(qc1.z, k2_.z, dB_); dB_ = fmaf(qc1.w, k2_.w, dB_); \
    dB_ = fmaf(qd1.x, k3_.x, dB_); dB_ = fmaf(qd1.y, k3_.y, dB_); dB_ = fmaf(qd1.z, k3_.z, dB_); dB_ = fmaf(qd1.w, k3_.w, dB_); \
    dA_ += __shfl_xor(dA_, 1, 4);  dA_ += __shfl_xor(dA_, 2, 4);                \
    dB_ += __shfl_xor(dB_, 1, 4);  dB_ += __shfl_xor(dB_, 2, 4);                \
    SA = dA_ * SCALE;  SB = dB_ * SCALE;                                        \
} while (0)

#define PV2(JJ, PA, PB) do {                                                    \
    const float* vr_ = &Vs[k0 + (JJ)][l16];                                     \
    float4 v0_ = *(const float4*)(vr_);      float4 v1_ = *(const float4*)(vr_ + 4);  \
    float4 v2_ = *(const float4*)(vr_ + 8);  float4 v3_ = *(const float4*)(vr_ + 12); \
    aA0.x = fmaf((PA), v0_.x, aA0.x); aA0.y = fmaf((PA), v0_.y, aA0.y);         \
    aA0.z = fmaf((PA), v0_.z, aA0.z); aA0.w = fmaf((PA), v0_.w, aA0.w);         \
    aA1.x = fmaf((PA), v1_.x, aA1.x); aA1.y = fmaf((PA), v1_.y, aA1.y);         \
    aA1.z = fmaf((PA), v1_.z, aA1.z); aA1.w = fmaf((PA), v1_.w, aA1.w);         \
    aA2.x = fmaf((PA), v2_.x, aA2.x); aA2.y = fmaf((PA), v2_.y, aA2.y);         \
    aA2.z = fmaf((PA), v2_.z, aA2.z); aA2.w = fmaf((PA), v2_.w, aA2.w);         \
    aA3.x = fmaf((PA), v3_.x, aA3.x); aA3.y = fmaf((PA), v3_.y, aA3.y);         \
    aA3.z = fmaf((PA), v3_.z, aA3.z); aA3.w = fmaf((PA), v3_.w, aA3.w);         \
    aB0.x = fmaf((PB), v0_.x, aB0.x); aB0.y = fmaf((PB), v0_.y, aB0.y);         \
    aB0.z = fmaf((PB), v0_.z, aB0.z); aB0.w = fmaf((PB), v0_.w, aB0.w);         \
    aB1.x = fmaf((PB), v1_.x, aB1.x); aB1.y = fmaf((PB), v1_.y, aB1.y);         \
    aB1.z = fmaf((PB), v1_.z, aB1.z); aB1.w = fmaf((PB), v1_.w, aB1.w);         \
    aB2.x = fmaf((PB), v2_.x, aB2.x); aB2.y = fmaf((PB), v2_.y, aB2.y);         \
    aB2.z = fmaf((PB), v2_.z, aB2.z); aB2.w = fmaf((PB), v2_.w, aB2.w);         \
    aB3.x = fmaf((PB), v3_.x, aB3.x); aB3.y = fmaf((PB), v3_.y, aB3.y);         \
    aB3.z = fmaf((PB), v3_.z, aB3.z); aB3.w = fmaf((PB), v3_.w, aB3.w);         \
} while (0)

__global__ __launch_bounds__(512) void attn_spatial(const float* __restrict__ QKV,
                                                    float* __restrict__ Out) {
    __shared__ float Ks[256][DH];   // 64 KiB
    __shared__ float Vs[256][DH];   // 64 KiB
    const int t    = threadIdx.x;
    const int nt   = blockIdx.x & 15;
    const int h    = (blockIdx.x >> 4) & 3;
    const int b    = blockIdx.x >> 6;
    const int base = nt * 256;
    const int l16  = (t & 3) * 16;
    const int rp   = t >> 2;          // rows rp and rp+128
    const size_t rowoff = (size_t)b * NTOK;

    const float* Kg  = QKV + (rowoff + base) * QKVC + 512  + h * DH;
    const float* Vg  = QKV + (rowoff + base) * QKVC + 1024 + h * DH;
    const float* QgA = QKV + (rowoff + base + rp) * QKVC + h * DH + l16;
    const float* QgB = QKV + (rowoff + base + rp + 128) * QKVC + h * DH + l16;

#pragma unroll
    for (int i = 0; i < 8; ++i) {
        int idx = t + 512 * i;
        int r = idx >> 4, c4 = (idx & 15) << 2;
        *(float4*)&Ks[r][c4] = *(const float4*)(Kg + (size_t)r * QKVC + c4);
        *(float4*)&Vs[r][c4] = *(const float4*)(Vg + (size_t)r * QKVC + c4);
    }

    float4 qa0 = *(const float4*)(QgA);      float4 qb0 = *(const float4*)(QgA + 4);
    float4 qc0 = *(const float4*)(QgA + 8);  float4 qd0 = *(const float4*)(QgA + 12);
    float4 qa1 = *(const float4*)(QgB);      float4 qb1 = *(const float4*)(QgB + 4);
    float4 qc1 = *(const float4*)(QgB + 8);  float4 qd1 = *(const float4*)(QgB + 12);

    float4 aA0 = make_float4(0.f, 0.f, 0.f, 0.f);
    float4 aA1 = aA0, aA2 = aA0, aA3 = aA0;
    float4 aB0 = aA0, aB1 = aA0, aB2 = aA0, aB3 = aA0;
    float mA = -INFINITY, lA = 0.f, mB = -INFINITY, lB = 0.f;

    __syncthreads();

    for (int k0 = 0; k0 < 256; k0 += 8) {
        float sA0, sA1, sA2, sA3, sA4, sA5, sA6, sA7;
        float sB0, sB1, sB2, sB3, sB4, sB5, sB6, sB7;
        QDOT2(0, sA0, sB0); QDOT2(1, sA1, sB1); QDOT2(2, sA2, sB2); QDOT2(3, sA3, sB3);
        QDOT2(4, sA4, sB4); QDOT2(5, sA5, sB5); QDOT2(6, sA6, sB6); QDOT2(7, sA7, sB7);

        {
            float cmax = fmaxf(fmaxf(fmaxf(sA0, sA1), fmaxf(sA2, sA3)),
                               fmaxf(fmaxf(sA4, sA5), fmaxf(sA6, sA7)));
            float mn   = fmaxf(mA, cmax);
            float corr = __expf(mA - mn);
            sA0 = __expf(sA0 - mn); sA1 = __expf(sA1 - mn); sA2 = __expf(sA2 - mn); sA3 = __expf(sA3 - mn);
            sA4 = __expf(sA4 - mn); sA5 = __expf(sA5 - mn); sA6 = __expf(sA6 - mn); sA7 = __expf(sA7 - mn);
            float ps = ((sA0 + sA1) + (sA2 + sA3)) + ((sA4 + sA5) + (sA6 + sA7));
            lA = fmaf(lA, corr, ps);
            mA = mn;
            aA0.x *= corr; aA0.y *= corr; aA0.z *= corr; aA0.w *= corr;
            aA1.x *= corr; aA1.y *= corr; aA1.z *= corr; aA1.w *= corr;
            aA2.x *= corr; aA2.y *= corr; aA2.z *= corr; aA2.w *= corr;
            aA3.x *= corr; aA3.y *= corr; aA3.z *= corr; aA3.w *= corr;
        }
        {
            float cmax = fmaxf(fmaxf(fmaxf(sB0, sB1), fmaxf(sB2, sB3)),
                               fmaxf(fmaxf(sB4, sB5), fmaxf(sB6, sB7)));
            float mn   = fmaxf(mB, cmax);
            float corr = __expf(mB - mn);
            sB0 = __expf(sB0 - mn); sB1 = __expf(sB1 - mn); sB2 = __expf(sB2 - mn); sB3 = __expf(sB3 - mn);
            sB4 = __expf(sB4 - mn); sB5 = __expf(sB5 - mn); sB6 = __expf(sB6 - mn); sB7 = __expf(sB7 - mn);
            float ps = ((sB0 + sB1) + (sB2 + sB3)) + ((sB4 + sB5) + (sB6 + sB7));
            lB = fmaf(lB, corr, ps);
            mB = mn;
            aB0.x *= corr; aB0.y *= corr; aB0.z *= corr; aB0.w *= corr;
            aB1.x *= corr; aB1.y *= corr; aB1.z *= corr; aB1.w *= corr;
            aB2.x *= corr; aB2.y *= corr; aB2.z *= corr; aB2.w *= corr;
            aB3.x *= corr; aB3.y *= corr; aB3.z *= corr; aB3.w *= corr;
        }

        PV2(0, sA0, sB0); PV2(1, sA1, sB1); PV2(2, sA2, sB2); PV2(3, sA3, sB3);
        PV2(4, sA4, sB4); PV2(5, sA5, sB5); PV2(6, sA6, sB6); PV2(7, sA7, sB7);
    }

    float invA = 1.f / lA, invB = 1.f / lB;
    float* opA = Out + ((size_t)(b * 4 + h) * NTOK + base + rp) * DH + l16;
    float* opB = Out + ((size_t)(b * 4 + h) * NTOK + base + rp + 128) * DH + l16;
    *(float4*)(opA)      = make_float4(aA0.x*invA, aA0.y*invA, aA0.z*invA, aA0.w*invA);
    *(float4*)(opA + 4)  = make_float4(aA1.x*invA, aA1.y*invA, aA1.z*invA, aA1.w*invA);
    *(float4*)(opA + 8)  = make_float4(aA2.x*invA, aA2.y*invA, aA2.z*invA, aA2.w*invA);
    *(float4*)(opA + 12) = make_float4(aA3.x*invA, aA3.y*invA, aA3.z*invA, aA3.w*invA);
    *(float4*)(opB)      = make_float4(aB0.x*invB, aB0.y*invB, aB0.z*invB, aB0.w*invB);
    *(float4*)(opB + 4)  = make_float4(aB1.x*invB, aB1.y*invB, aB1.z*invB, aB1.w*invB);
    *(float4*)(opB + 8)  = make_float4(aB2.x*invB, aB2.y*invB, aB2.z*invB, aB2.w*invB);
    *(float4*)(opB + 12) = make_float4(aB3.x*invB, aB3.y*invB, aB3.z*invB, aB3.w*invB);
}

// ================= Temporal attention (unchanged) =============
__global__ __launch_bounds__(256, 4) void attn_temporal(const float* __restrict__ QKV,
                                                        float* __restrict__ Out) {
    const int t    = threadIdx.x;
    const int l    = t & 3;
    const int row  = blockIdx.x * 64 + (t >> 2);
    const int tt   = row & 15;
    const int s    = (row >> 4) & 255;
    const int h    = (row >> 12) & 3;
    const int b    = row >> 14;
    const int head = 4 + h;
    const int token = s * 16 + tt;
    const size_t rowoff = (size_t)b * NTOK;

    const float* Qp = QKV + (rowoff + token) * QKVC + head * DH + l * 16;
    const float* Kb = QKV + (rowoff + s * 16) * QKVC + 512  + head * DH + l * 16;
    const float* Vb = QKV + (rowoff + s * 16) * QKVC + 1024 + head * DH + l * 16;

    float q[16];
#pragma unroll
    for (int c = 0; c < 16; c += 4) *(float4*)&q[c] = *(const float4*)(Qp + c);

    float sc[16];
    float mx = -INFINITY;
#pragma unroll
    for (int j = 0; j < 16; ++j) {
        const float* kr = Kb + (size_t)j * QKVC;
        float d = 0.f;
#pragma unroll
        for (int c = 0; c < 16; c += 4) {
            float4 kv = *(const float4*)(kr + c);
            d = fmaf(q[c], kv.x, d); d = fmaf(q[c+1], kv.y, d);
            d = fmaf(q[c+2], kv.z, d); d = fmaf(q[c+3], kv.w, d);
        }
        d += __shfl_xor(d, 1, 4);
        d += __shfl_xor(d, 2, 4);
        sc[j] = d * SCALE;
        mx = fmaxf(mx, sc[j]);
    }
    float lsum = 0.f;
#pragma unroll
    for (int j = 0; j < 16; ++j) { sc[j] = __expf(sc[j] - mx); lsum += sc[j]; }
    float inv = 1.f / lsum;

    float acc[16];
#pragma unroll
    for (int c = 0; c < 16; ++c) acc[c] = 0.f;
#pragma unroll
    for (int j = 0; j < 16; ++j) {
        const float* vr = Vb + (size_t)j * QKVC;
        float p = sc[j];
#pragma unroll
        for (int c = 0; c < 16; c += 4) {
            float4 vv = *(const float4*)(vr + c);
            acc[c]   = fmaf(p, vv.x, acc[c]);   acc[c+1] = fmaf(p, vv.y, acc[c+1]);
            acc[c+2] = fmaf(p, vv.z, acc[c+2]); acc[c+3] = fmaf(p, vv.w, acc[c+3]);
        }
    }
    float* op = Out + (size_t)(NBATCH * 4) * NTOK * DH
                    + ((size_t)(b * 4 + h) * NTOK + token) * DH + l * 16;
#pragma unroll
    for (int c = 0; c < 16; c += 4)
        *(float4*)(op + c) = make_float4(acc[c]*inv, acc[c+1]*inv, acc[c+2]*inv, acc[c+3]*inv);
}

extern "C" void kernel_launch(void* const* d_in, const int* in_sizes, int n_in,
                              void* d_out, int out_size, void* d_ws, size_t ws_size,
                              hipStream_t stream) {
    const float* x = (const float*)d_in[0];   // [8,4096,512] fp32
    const float* w = (const float*)d_in[1];   // [512,1536]  fp32
    float* out = (float*)d_out;               // [2,8,4,4096,64] fp32 = 64 MiB
    float* qkv = (float*)d_ws;                // 192 MiB scratch

    // d_out doubles as xh/xl staging (exactly 64 MiB) until the attention
    // kernels overwrite every byte of it — same-stream ordering guarantees safety.
    unsigned short* xh = (unsigned short*)d_out;
    unsigned short* xl = xh + (size_t)NBATCH * NTOK * DIMX;

    split_x<<<dim3(16384), 256, 0, stream>>>(x, xh, xl);
    qkv_gemm_mfma<<<dim3(3072), 256, 0, stream>>>(xh, xl, w, qkv);
    attn_spatial<<<dim3(512), 512, 0, stream>>>(qkv, out);
    attn_temporal<<<dim3(2048), 256, 0, stream>>>(qkv, out);
}